// Round 2
// baseline (688.409 us; speedup 1.0000x reference)
//
#include <hip/hip_runtime.h>

// NeuralODE: z0 = enc(y0); 100 x Tsit5 steps of f = W3 tanh(W2 tanh(W1 y + b1) + b2) + b3;
// outputs ys = dec(z_t), zs = z_t.  One wave (64 thr) per 16 batch elements, grid 256.
// Latency-bound (1 wave/CU structural): this version is critical-path surgery —
// dual MFMA accumulators (chain 6->3), pre-scaled W1/W2 by 2/ln2 (tanh drops mul),
// balanced-tree stage combos, decoder in registers (no LDS at all).
//
// GEMM orientation: D[row, elem] = W[row, k] * Act[k, elem] with mfma_f32_16x16x32_f16.
// Lane l = (e = l&15, q = l>>4). C/D: lane holds rows p = 16t+4q+r (t = M-tile, r = reg).
// Consumer weight k-columns pre-shuffled by kappa so producer C/D regs ARE the consumer
// B-fragment: B slot j of K-tile kt == state[8*kt + j], state[4t+r] = row 16t+4q+r.
// 3-term f16 hi/lo split (Whi*Bhi + Wlo*Bhi + Whi*Blo) ~2^-22 per-product error.

typedef __attribute__((ext_vector_type(8))) _Float16 half8;
typedef __attribute__((ext_vector_type(4))) float f32x4;

static constexpr int TN = 101;
static constexpr int BN = 4096;
static constexpr float SC = 2.8853900817779268f;  // 2/ln2

#define MFMA(a, b, c) __builtin_amdgcn_mfma_f32_16x16x32_f16((a), (b), (c), 0, 0, 0)

__device__ __forceinline__ float tanh_pre(float t) {
  // input pre-scaled by 2/ln2: tanh(x) = 1 - 2/(1+2^t); exact at +/-inf.
  float e = __builtin_amdgcn_exp2f(t);
  float r = __builtin_amdgcn_rcpf(e + 1.0f);
  return __builtin_fmaf(-2.0f, r, 1.0f);
}

__device__ __forceinline__ void split8(const float* v, half8& hi, half8& lo) {
#pragma unroll
  for (int j = 0; j < 8; ++j) {
    _Float16 h = (_Float16)v[j];
    hi[j] = h;
    lo[j] = (_Float16)(v[j] - (float)h);
  }
}

// A-fragment for a weight whose k-columns are consumed kappa-shuffled:
// slot j of lane q, K-tile kt  <-  W[row][kt*32 + 16*(j>>2) + 4*q + (j&3)], times scale
__device__ __forceinline__ void load_wfrag(const float* __restrict__ W, int C, int row, int q,
                                           int kt, float scale, half8& hi, half8& lo) {
  const float* p = W + row * C + kt * 32 + 4 * q;
  float v[8] __attribute__((aligned(16)));
  *(f32x4*)(v) = *(const f32x4*)(p);
  *(f32x4*)(v + 4) = *(const f32x4*)(p + 16);
#pragma unroll
  for (int j = 0; j < 8; ++j) v[j] *= scale;
  split8(v, hi, lo);
}

__device__ __forceinline__ f32x4 vfma(float s, f32x4 a, f32x4 b) {
  f32x4 r;
#pragma unroll
  for (int j = 0; j < 4; ++j) r[j] = __builtin_fmaf(s, a[j], b[j]);
  return r;
}
__device__ __forceinline__ f32x4 vmul(float s, f32x4 a) {
  f32x4 r;
#pragma unroll
  for (int j = 0; j < 4; ++j) r[j] = s * a[j];
  return r;
}

__global__ __launch_bounds__(64, 1) void node_kernel(
    const float* __restrict__ ts, const float* __restrict__ y0,
    const float* __restrict__ encW, const float* __restrict__ encb,
    const float* __restrict__ W1, const float* __restrict__ b1,
    const float* __restrict__ W2, const float* __restrict__ b2,
    const float* __restrict__ W3, const float* __restrict__ b3,
    const float* __restrict__ decW, const float* __restrict__ decb,
    float* __restrict__ out) {
  const int l = threadIdx.x;
  const int lm = l & 15;
  const int q = l >> 4;
  const int eg = blockIdx.x * 16 + lm;

  // ---- persistent MLP weight fragments (f16 hi+lo); W1,W2 pre-scaled by 2/ln2 ----
  half8 w1h[2][2], w1l[2][2], w2h[2], w2l[2], w3h[4], w3l[4];
#pragma unroll
  for (int mt = 0; mt < 2; ++mt) {
#pragma unroll
    for (int kt = 0; kt < 2; ++kt)
      load_wfrag(W1, 64, 16 * mt + lm, q, kt, SC, w1h[mt][kt], w1l[mt][kt]);
    load_wfrag(W2, 32, 16 * mt + lm, q, 0, SC, w2h[mt], w2l[mt]);
  }
#pragma unroll
  for (int mt = 0; mt < 4; ++mt) load_wfrag(W3, 32, 16 * mt + lm, q, 0, 1.0f, w3h[mt], w3l[mt]);

  f32x4 b1f[2], b2f[2], b3f[4];
#pragma unroll
  for (int mt = 0; mt < 2; ++mt) {
    b1f[mt] = vmul(SC, *(const f32x4*)(b1 + 16 * mt + 4 * q));
    b2f[mt] = vmul(SC, *(const f32x4*)(b2 + 16 * mt + 4 * q));
  }
#pragma unroll
  for (int mt = 0; mt < 4; ++mt) b3f[mt] = *(const f32x4*)(b3 + 16 * mt + 4 * q);

  // ---- decoder frags in registers (single f16: decoder error does not feed back) ----
  half8 dw[4][2];
  f32x4 db[4];
#pragma unroll
  for (int mt = 0; mt < 4; ++mt) {
#pragma unroll
    for (int kt = 0; kt < 2; ++kt) {
      const float* p = decW + (16 * mt + lm) * 64 + kt * 32 + 4 * q;
      float v[8] __attribute__((aligned(16)));
      *(f32x4*)(v) = *(const f32x4*)(p);
      *(f32x4*)(v + 4) = *(const f32x4*)(p + 16);
      half8 h;
#pragma unroll
      for (int j = 0; j < 8; ++j) h[j] = (_Float16)v[j];
      dw[mt][kt] = h;
    }
    db[mt] = *(const f32x4*)(decb + 16 * mt + 4 * q);
  }

  f32x4 z[4];

  // ---- encoder: z0 = encW * y0^T + encb (enc cols in TRUE order) ----
  {
    const float* yp = y0 + (size_t)eg * 64;
    float v[16] __attribute__((aligned(16)));
    *(f32x4*)(v) = *(const f32x4*)(yp + 8 * q);
    *(f32x4*)(v + 4) = *(const f32x4*)(yp + 8 * q + 4);
    *(f32x4*)(v + 8) = *(const f32x4*)(yp + 32 + 8 * q);
    *(f32x4*)(v + 12) = *(const f32x4*)(yp + 32 + 8 * q + 4);
    half8 xh[2], xl[2];
    split8(v, xh[0], xl[0]);
    split8(v + 8, xh[1], xl[1]);
#pragma unroll
    for (int mt = 0; mt < 4; ++mt) {
      const float* p0 = encW + (16 * mt + lm) * 64 + 8 * q;
      float w[8] __attribute__((aligned(16)));
      half8 eh, el;
      f32x4 a = *(const f32x4*)(encb + 16 * mt + 4 * q);
      f32x4 b = {0.0f, 0.0f, 0.0f, 0.0f};
      *(f32x4*)(w) = *(const f32x4*)(p0);
      *(f32x4*)(w + 4) = *(const f32x4*)(p0 + 4);
      split8(w, eh, el);
      a = MFMA(eh, xh[0], a);
      b = MFMA(el, xh[0], b);
      b = MFMA(eh, xl[0], b);
      *(f32x4*)(w) = *(const f32x4*)(p0 + 32);
      *(f32x4*)(w + 4) = *(const f32x4*)(p0 + 36);
      split8(w, eh, el);
      a = MFMA(eh, xh[1], a);
      b = MFMA(el, xh[1], b);
      b = MFMA(eh, xl[1], b);
      z[mt] = a + b;
    }
  }

  // ---- f eval: dual accumulators to halve MFMA chain depth ----
  auto evalf = [&](const f32x4 (&yv)[4], f32x4 (&kv)[4]) {
    half8 yh[2], yl[2];
    split8((const float*)&yv[0], yh[0], yl[0]);
    split8((const float*)&yv[2], yh[1], yl[1]);
    float h1[8] __attribute__((aligned(16)));
    float h2[8] __attribute__((aligned(16)));
#pragma unroll
    for (int mt = 0; mt < 2; ++mt) {
      f32x4 a = b1f[mt];
      f32x4 b = {0.0f, 0.0f, 0.0f, 0.0f};
      a = MFMA(w1h[mt][0], yh[0], a);   // chain a: hh0, hh1, lh1
      b = MFMA(w1l[mt][0], yh[0], b);   // chain b: lh0, hl0, hl1
      b = MFMA(w1h[mt][0], yl[0], b);
      a = MFMA(w1h[mt][1], yh[1], a);
      a = MFMA(w1l[mt][1], yh[1], a);
      b = MFMA(w1h[mt][1], yl[1], b);
      f32x4 s = a + b;
#pragma unroll
      for (int r = 0; r < 4; ++r) h1[4 * mt + r] = tanh_pre(s[r]);
    }
    half8 hh, hl;
    split8(h1, hh, hl);
#pragma unroll
    for (int mt = 0; mt < 2; ++mt) {
      f32x4 a = b2f[mt];
      f32x4 b = {0.0f, 0.0f, 0.0f, 0.0f};
      a = MFMA(w2h[mt], hh, a);
      b = MFMA(w2l[mt], hh, b);
      a = MFMA(w2h[mt], hl, a);
      f32x4 s = a + b;
#pragma unroll
      for (int r = 0; r < 4; ++r) h2[4 * mt + r] = tanh_pre(s[r]);
    }
    split8(h2, hh, hl);
#pragma unroll
    for (int mt = 0; mt < 4; ++mt) {
      f32x4 a = b3f[mt];
      f32x4 b = {0.0f, 0.0f, 0.0f, 0.0f};
      a = MFMA(w3h[mt], hh, a);
      b = MFMA(w3l[mt], hh, b);
      a = MFMA(w3h[mt], hl, a);
      kv[mt] = a + b;
    }
  };

  auto store_z = [&](const f32x4 (&x)[4], int s) {
    float* zb = out + (size_t)BN * TN * 64 + ((size_t)eg * TN + s) * 64;
#pragma unroll
    for (int t = 0; t < 4; ++t) *(f32x4*)(zb + 16 * t + 4 * q) = x[t];
  };

  auto dec_store = [&](const f32x4 (&x)[4], int s) {
    half8 xh[2];
    const float* xf = (const float*)&x[0];
#pragma unroll
    for (int j = 0; j < 8; ++j) {
      xh[0][j] = (_Float16)xf[j];
      xh[1][j] = (_Float16)xf[8 + j];
    }
    float* yb = out + ((size_t)eg * TN + s) * 64;
#pragma unroll
    for (int mt = 0; mt < 4; ++mt) {
      f32x4 a = db[mt];
      a = MFMA(dw[mt][0], xh[0], a);
      a = MFMA(dw[mt][1], xh[1], a);
      *(f32x4*)(yb + 16 * mt + 4 * q) = a;
    }
  };

  store_z(z, 0);
  dec_store(z, 0);

  const float dt = (ts[TN - 1] - ts[0]) / (float)(TN - 1);
  const float dA21 = dt * 0.161f;
  const float dA31 = dt * -0.008480655492356989f, dA32 = dt * 0.335480655492357f;
  const float dA41 = dt * 2.8971530571054935f, dA42 = dt * -6.359448489975075f,
              dA43 = dt * 4.3622954328695815f;
  const float dA51 = dt * 5.325864828439257f, dA52 = dt * -11.748883564062828f,
              dA53 = dt * 7.4955393428898365f, dA54 = dt * -0.09249506636175525f;
  const float dA61 = dt * 5.86145544294642f, dA62 = dt * -12.92096931784711f,
              dA63 = dt * 8.159367898576159f, dA64 = dt * -0.071584973281401f,
              dA65 = dt * -0.028269050394068383f;
  const float dB1 = dt * 0.09646076681806523f, dB2 = dt * 0.01f, dB3 = dt * 0.4798896504144996f,
              dB4 = dt * 1.379008574103742f, dB5 = dt * -3.290069515436081f,
              dB6 = dt * 2.324710524099774f;

#pragma nounroll
  for (int s = 1; s < TN; ++s) {
    f32x4 k1[4], k2[4], k3[4], k4[4], k5[4], k6[4], y[4];
    evalf(z, k1);
#pragma unroll
    for (int t = 0; t < 4; ++t) y[t] = vfma(dA21, k1[t], z[t]);
    evalf(y, k2);
#pragma unroll
    for (int t = 0; t < 4; ++t) y[t] = z[t] + vfma(dA32, k2[t], vmul(dA31, k1[t]));
    evalf(y, k3);
#pragma unroll
    for (int t = 0; t < 4; ++t) {
      f32x4 t1 = vfma(dA42, k2[t], vmul(dA41, k1[t]));
      y[t] = z[t] + vfma(dA43, k3[t], t1);
    }
    evalf(y, k4);
#pragma unroll
    for (int t = 0; t < 4; ++t) {
      f32x4 t1 = vfma(dA52, k2[t], vmul(dA51, k1[t]));
      f32x4 t2 = vfma(dA54, k4[t], vmul(dA53, k3[t]));
      y[t] = z[t] + (t1 + t2);
    }
    evalf(y, k5);
#pragma unroll
    for (int t = 0; t < 4; ++t) {
      f32x4 t1 = vfma(dA62, k2[t], vmul(dA61, k1[t]));
      f32x4 t2 = vfma(dA64, k4[t], vmul(dA63, k3[t]));
      f32x4 t3 = vmul(dA65, k5[t]);
      y[t] = z[t] + (t1 + (t2 + t3));
    }
    evalf(y, k6);
#pragma unroll
    for (int t = 0; t < 4; ++t) {
      f32x4 t1 = vfma(dB2, k2[t], vmul(dB1, k1[t]));
      f32x4 t2 = vfma(dB4, k4[t], vmul(dB3, k3[t]));
      f32x4 t3 = vfma(dB6, k6[t], vmul(dB5, k5[t]));
      z[t] = z[t] + (t1 + (t2 + t3));
    }
    store_z(z, s);
    dec_store(z, s);
  }
}

extern "C" void kernel_launch(void* const* d_in, const int* in_sizes, int n_in,
                              void* d_out, int out_size, void* d_ws, size_t ws_size,
                              hipStream_t stream) {
  const float* ts = (const float*)d_in[0];
  const float* y0 = (const float*)d_in[1];
  const float* encW = (const float*)d_in[2];
  const float* encb = (const float*)d_in[3];
  const float* W1 = (const float*)d_in[4];
  const float* b1 = (const float*)d_in[5];
  const float* W2 = (const float*)d_in[6];
  const float* b2 = (const float*)d_in[7];
  const float* W3 = (const float*)d_in[8];
  const float* b3 = (const float*)d_in[9];
  const float* decW = (const float*)d_in[10];
  const float* decb = (const float*)d_in[11];
  node_kernel<<<BN / 16, 64, 0, stream>>>(ts, y0, encW, encb, W1, b1, W2, b2, W3, b3, decW, decb,
                                          (float*)d_out);
}